// Round 8
// baseline (171.352 us; speedup 1.0000x reference)
//
#include <hip/hip_runtime.h>
#include <hip/hip_bf16.h>
#include <math.h>

#define N_NODES 50000
#define N_EDGES 800000
#define F 64
#define CUTOFF2 100.0f

#define NPB 50                 // nodes per bucket
#define NBUCKET 1000           // 50000 / 50 exactly
#define CAP 512                // records per bucket (mean ~225, sigma ~15)
#define NODE_BLOCKS 782        // ceil(3125 node-tiles / 4 waves-per-block)
#define PREP_BLOCKS 3125       // 800000 / 256 exactly

typedef __attribute__((ext_vector_type(8))) short bf16x8;   // 8 bf16 = 4 VGPR
typedef __attribute__((ext_vector_type(4))) float f32x4;    // MFMA C/D

__device__ __forceinline__ float silu_f(float v) {
    return v / (1.0f + __expf(-v));
}

// f32 -> bf16 bits, round-to-nearest-even
__device__ __forceinline__ unsigned short bf16_rne(float f) {
    unsigned int u = __float_as_uint(f);
    unsigned int r = (u + 0x7FFFu + ((u >> 16) & 1u)) >> 16;
    return (unsigned short)r;
}
__device__ __forceinline__ float bf16_f32(unsigned short h) {
    return __uint_as_float(((unsigned int)h) << 16);
}

// ---------------------------------------------------------------------------
// 16-row GEMM tile vs 64x64 row-major W (3-term bf16 split ~ f32 accuracy).
// MFMA f32_16x16x32_bf16 layouts (refcheck-verified rounds 3-7):
//   A: row = lane&15, k = (lane>>4)*8 + j
//   B: col = lane&15, k = (lane>>4)*8 + j
//   D: col = lane&15, row = (lane>>4)*4 + reg
// ---------------------------------------------------------------------------
__device__ __forceinline__ void gemm16_store(
    const bf16x8 (&Ah)[2], const bf16x8 (&Al)[2],
    const float* __restrict__ W, const float* __restrict__ bias,
    float* __restrict__ dst, int n0, int r, int g)
{
    #pragma unroll
    for (int c = 0; c < 4; ++c) {
        f32x4 acc = {0.f, 0.f, 0.f, 0.f};
        #pragma unroll
        for (int t = 0; t < 2; ++t) {
            bf16x8 bh, bl;
            #pragma unroll
            for (int j = 0; j < 8; ++j) {
                const float wv = W[(size_t)(t * 32 + g * 8 + j) * F + c * 16 + r];
                const unsigned short hb = bf16_rne(wv);
                bh[j] = (short)hb;
                bl[j] = (short)bf16_rne(wv - bf16_f32(hb));
            }
            acc = __builtin_amdgcn_mfma_f32_16x16x32_bf16(Ah[t], bh, acc, 0, 0, 0);
            acc = __builtin_amdgcn_mfma_f32_16x16x32_bf16(Al[t], bh, acc, 0, 0, 0);
            acc = __builtin_amdgcn_mfma_f32_16x16x32_bf16(Ah[t], bl, acc, 0, 0, 0);
        }
        const float bb = bias[c * 16 + r];
        #pragma unroll
        for (int rg = 0; rg < 4; ++rg) {
            dst[(size_t)(n0 + g * 4 + rg) * F + c * 16 + r] = acc[rg] + bb;
        }
    }
}

// ---------------------------------------------------------------------------
// Kernel 1 (fused): blocks [0, NODE_BLOCKS) do node projections via MFMA;
// blocks [NODE_BLOCKS, ...) do edge prep: cutoff test + radial MLP +
// scatter into per-target-bucket regions.
// Record (32B): {src, tgt, r0, r1, r2, r3, cutoff, pad}.
// ---------------------------------------------------------------------------
__global__ __launch_bounds__(256) void node_prep_kernel(
    const float* __restrict__ x, const float* __restrict__ Wp,
    const float* __restrict__ bp, const float* __restrict__ W1,
    const float* __restrict__ b1,
    const int* __restrict__ ei, const float* __restrict__ pos,
    const float* __restrict__ Wr1, const float* __restrict__ br1,
    const float* __restrict__ Wr2, const float* __restrict__ br2,
    float* __restrict__ out, float* __restrict__ h1,
    float* __restrict__ recs, int* __restrict__ counts)
{
    if (blockIdx.x < NODE_BLOCKS) {
        // ---- node part: one wave per 16-node tile (50000 = 3125*16) ----
        const int lane = threadIdx.x & 63;
        const int gw   = blockIdx.x * 4 + (threadIdx.x >> 6);
        if (gw >= N_NODES / 16) return;
        const int n0 = gw * 16;
        const int r = lane & 15, g = lane >> 4;

        bf16x8 Ah[2], Al[2];
        #pragma unroll
        for (int t = 0; t < 2; ++t) {
            const float* xp = x + (size_t)(n0 + r) * F + t * 32 + g * 8;
            #pragma unroll
            for (int j = 0; j < 8; ++j) {
                const float v = xp[j];
                const unsigned short hb = bf16_rne(v);
                Ah[t][j] = (short)hb;
                Al[t][j] = (short)bf16_rne(v - bf16_f32(hb));
            }
        }
        gemm16_store(Ah, Al, Wp, bp, out, n0, r, g);
        gemm16_store(Ah, Al, W1, b1, h1, n0, r, g);
    } else {
        // ---- prep part: one thread per edge ----
        const int e = (blockIdx.x - NODE_BLOCKS) * 256 + threadIdx.x;
        if (e >= N_EDGES) return;
        const int src = ei[e];
        const int tgt = ei[N_EDGES + e];
        const float dx = pos[3 * tgt + 0] - pos[3 * src + 0];
        const float dy = pos[3 * tgt + 1] - pos[3 * src + 1];
        const float dz = pos[3 * tgt + 2] - pos[3 * src + 2];
        const float d2 = dx * dx + dy * dy + dz * dz;
        if (d2 >= CUTOFF2) return;

        const float d = sqrtf(d2);
        float a0 = br2[0], a1 = br2[1], a2 = br2[2], a3 = br2[3];
        #pragma unroll
        for (int i = 0; i < 16; ++i) {
            const float t = silu_f(fmaf(d, Wr1[i], br1[i]));
            a0 = fmaf(t, Wr2[i * 4 + 0], a0);
            a1 = fmaf(t, Wr2[i * 4 + 1], a1);
            a2 = fmaf(t, Wr2[i * 4 + 2], a2);
            a3 = fmaf(t, Wr2[i * 4 + 3], a3);
        }
        const float r0 = silu_f(a0), r1 = silu_f(a1);
        const float r2 = silu_f(a2), r3 = silu_f(a3);
        const float cut = 1.0f - d2 * 0.01f;    // in (0,1] when d2 < 100

        const int b   = tgt / NPB;
        const int idx = atomicAdd(&counts[b], 1);   // 1000 spread int counters
        if (idx < CAP) {
            float4* p = (float4*)(recs + ((size_t)b * CAP + idx) * 8);
            p[0] = make_float4(__int_as_float(src), __int_as_float(tgt), r0, r1);
            p[1] = make_float4(r2, r3, cut, 0.0f);
        }
    }
}

// ---------------------------------------------------------------------------
// Kernel 2: edge MLP via MFMA + LDS-aggregated scatter.
// R8 changes vs R7:
//  - unsafeAtomicAdd on LDS agg -> guaranteed fire-and-forget ds_add_f32
//    (plain atomicAdd(float*) may lower to a CAS loop: 2 dependent LDS
//    round-trips x16/tile = the suspected R6/R7 stall)
//  - NPB 25->50: ~14 tiles/block -> 3.5 tiles/wave (pipeline has depth)
//  - 2-deep software pipeline: next tile's records + h1 gather issued
//    before current tile's MFMA/epilogue (hides ~600cy L3 gather latency)
// ---------------------------------------------------------------------------
__global__ __launch_bounds__(256) void edge_main_kernel(
    const float* __restrict__ recs, const int* __restrict__ counts,
    const float* __restrict__ h1, const float* __restrict__ W1,
    const float* __restrict__ W2, const float* __restrict__ b2,
    float* __restrict__ out)
{
    __shared__ __align__(16) float agg[NPB][F + 1];   // 13000 B, +1 pad
    __shared__ __align__(16) short sB[4][2][64][8];   // 4096 B
    __shared__ __align__(16) float sW1[4][2][4][8];   // 1024 B

    const int tid  = threadIdx.x;
    const int blk  = blockIdx.x;
    const int cnt  = min(counts[blk], CAP);
    if (cnt == 0) return;   // uniform across block; out untouched (+=0)

    const int lane = tid & 63;
    const int w    = tid >> 6;
    const int r    = lane & 15, g = lane >> 4;
    const int node0 = blk * NPB;

    // Fill sB: W2[k][n] -> sB[n>>4][k>>5][((k>>3)&3)*16 + (n&15)][k&7]
    #pragma unroll
    for (int q = 0; q < 4; ++q) {
        const int f = tid * 16 + q * 4;
        float tmp[4];
        *(float4*)tmp = *(const float4*)&W2[f];
        #pragma unroll
        for (int m = 0; m < 4; ++m) {
            const int ff = f + m;
            const int k = ff >> 6, n = ff & 63;
            sB[n >> 4][k >> 5][(((k >> 3) & 3) << 4) | (n & 15)][k & 7] =
                (short)bf16_rne(tmp[m]);
        }
    }
    // Fill sW1: one element per thread (256 = 4*64 exactly).
    {
        const int i = tid >> 6, k = tid & 63;
        sW1[i][k >> 5][(k >> 3) & 3][k & 7] = W1[(size_t)(F + i) * F + k];
    }
    // Zero agg.
    for (int i = tid; i < NPB * (F + 1); i += 256)
        agg[i / (F + 1)][i % (F + 1)] = 0.f;
    __syncthreads();

    float b2c[4];
    #pragma unroll
    for (int c = 0; c < 4; ++c) b2c[c] = b2[c * 16 + r];

    const float* rbase = recs + (size_t)blk * CAP * 8;
    const int ntiles = (cnt + 15) >> 4;

    // ---- 2-deep pipelined tile loop (wave w owns s = w, w+4, ...) ----
    float4 raA, rbA, q00A, q01A, q10A, q11A;
    if (w < ntiles) {
        const int er = min((w << 4) + r, cnt - 1);
        raA = *(const float4*)(rbase + (size_t)er * 8);
        rbA = *(const float4*)(rbase + (size_t)er * 8 + 4);
        const float* hp = h1 + (size_t)__float_as_int(raA.x) * F + g * 8;
        q00A = *(const float4*)(hp);
        q01A = *(const float4*)(hp + 4);
        q10A = *(const float4*)(hp + 32);
        q11A = *(const float4*)(hp + 36);
    }

    for (int s = w; s < ntiles; s += 4) {
        // Issue next tile's record loads first (independent of A-state).
        // Whenever the loop continues, sn == s+4; on the last iteration the
        // clamp just re-reads a valid tile whose data is discarded.
        const int sn  = min(s + 4, ntiles - 1);
        const int ern = min((sn << 4) + r, cnt - 1);
        const float4 raB = *(const float4*)(rbase + (size_t)ern * 8);
        const float4 rbB = *(const float4*)(rbase + (size_t)ern * 8 + 4);

        const int base = s << 4;

        // Epilogue metadata (per-g quarter owns 4 rows of the D tile).
        int   lrow_e[4]; float cut_e[4];
        #pragma unroll
        for (int rg = 0; rg < 4; ++rg) {
            lrow_e[rg] = __shfl(__float_as_int(raA.y), g * 4 + rg) - node0;
            cut_e[rg]  = __shfl(rbA.z, g * 4 + rg);
        }

        float hv[2][8];
        hv[0][0] = q00A.x; hv[0][1] = q00A.y; hv[0][2] = q00A.z; hv[0][3] = q00A.w;
        hv[0][4] = q01A.x; hv[0][5] = q01A.y; hv[0][6] = q01A.z; hv[0][7] = q01A.w;
        hv[1][0] = q10A.x; hv[1][1] = q10A.y; hv[1][2] = q10A.z; hv[1][3] = q10A.w;
        hv[1][4] = q11A.x; hv[1][5] = q11A.y; hv[1][6] = q11A.z; hv[1][7] = q11A.w;

        // Rank-4 radial update + silu, then cvt to bf16 A-fragments.
        bf16x8 ah[2];
        #pragma unroll
        for (int t = 0; t < 2; ++t) {
            float w0[8], w1a[8], w2a[8], w3a[8];
            *(float4*)&w0[0]  = *(const float4*)&sW1[0][t][g][0];
            *(float4*)&w0[4]  = *(const float4*)&sW1[0][t][g][4];
            *(float4*)&w1a[0] = *(const float4*)&sW1[1][t][g][0];
            *(float4*)&w1a[4] = *(const float4*)&sW1[1][t][g][4];
            *(float4*)&w2a[0] = *(const float4*)&sW1[2][t][g][0];
            *(float4*)&w2a[4] = *(const float4*)&sW1[2][t][g][4];
            *(float4*)&w3a[0] = *(const float4*)&sW1[3][t][g][0];
            *(float4*)&w3a[4] = *(const float4*)&sW1[3][t][g][4];
            #pragma unroll
            for (int j = 0; j < 8; ++j) {
                float h = hv[t][j];
                h = fmaf(raA.z, w0[j],  h);
                h = fmaf(raA.w, w1a[j], h);
                h = fmaf(rbA.x, w2a[j], h);
                h = fmaf(rbA.y, w3a[j], h);
                ah[t][j] = (short)bf16_rne(silu_f(h));
            }
        }

        // Issue next tile's h1 gather NOW (raB has arrived during the VALU
        // above); its latency hides under the MFMA + epilogue below.
        const float* hpB = h1 + (size_t)__float_as_int(raB.x) * F + g * 8;
        const float4 q00B = *(const float4*)(hpB);
        const float4 q01B = *(const float4*)(hpB + 4);
        const float4 q10B = *(const float4*)(hpB + 32);
        const float4 q11B = *(const float4*)(hpB + 36);

        // [16 x 64] @ W2 via 8 MFMAs; B-fragment = 1 ds_read_b128 each.
        f32x4 acc[4] = {};
        #pragma unroll
        for (int t = 0; t < 2; ++t)
            #pragma unroll
            for (int c = 0; c < 4; ++c) {
                const bf16x8 bb = *(const bf16x8*)&sB[c][t][lane][0];
                acc[c] = __builtin_amdgcn_mfma_f32_16x16x32_bf16(
                    ah[t], bb, acc[c], 0, 0, 0);
            }

        // Epilogue: bias + silu + cutoff -> ds_add_f32 (fire-and-forget).
        #pragma unroll
        for (int rg = 0; rg < 4; ++rg) {
            if (base + g * 4 + rg < cnt) {
                #pragma unroll
                for (int c = 0; c < 4; ++c) {
                    const float v = silu_f(acc[c][rg] + b2c[c]) * cut_e[rg];
                    unsafeAtomicAdd(&agg[lrow_e[rg]][c * 16 + r], v);
                }
            }
        }

        // Rotate pipeline state.
        raA = raB; rbA = rbB;
        q00A = q00B; q01A = q01B; q10A = q10B; q11A = q11B;
    }

    __syncthreads();
    // Flush: bucket rows are exclusive to this block -> plain +=.
    for (int i = tid; i < NPB * F; i += 256) {
        out[(size_t)(node0 + (i >> 6)) * F + (i & 63)] += agg[i >> 6][i & 63];
    }
}

extern "C" void kernel_launch(void* const* d_in, const int* in_sizes, int n_in,
                              void* d_out, int out_size, void* d_ws, size_t ws_size,
                              hipStream_t stream) {
    const float* x   = (const float*)d_in[0];
    const int*   ei  = (const int*)d_in[1];
    const float* pos = (const float*)d_in[2];
    const float* Wp  = (const float*)d_in[3];
    const float* bp  = (const float*)d_in[4];
    const float* W1  = (const float*)d_in[5];
    const float* b1  = (const float*)d_in[6];
    const float* W2  = (const float*)d_in[7];
    const float* b2  = (const float*)d_in[8];
    const float* Wr1 = (const float*)d_in[9];
    const float* br1 = (const float*)d_in[10];
    const float* Wr2 = (const float*)d_in[11];
    const float* br2 = (const float*)d_in[12];
    float* out = (float*)d_out;

    // workspace: [counts 8KB][h1 12.8MB][recs 1000*512*32B = 16.4MB]
    char*  ws     = (char*)d_ws;
    int*   counts = (int*)ws;
    float* h1     = (float*)(ws + 8192);
    float* recs   = (float*)(ws + 8192 + (size_t)N_NODES * F * sizeof(float));

    hipMemsetAsync(counts, 0, NBUCKET * sizeof(int), stream);
    node_prep_kernel<<<NODE_BLOCKS + PREP_BLOCKS, 256, 0, stream>>>(
        x, Wp, bp, W1, b1, ei, pos, Wr1, br1, Wr2, br2,
        out, h1, recs, counts);
    edge_main_kernel<<<NBUCKET, 256, 0, stream>>>(
        recs, counts, h1, W1, W2, b2, out);
}